// Round 9
// baseline (169.248 us; speedup 1.0000x reference)
//
#include <hip/hip_runtime.h>

typedef unsigned short u16;
typedef unsigned int u32;
typedef __attribute__((ext_vector_type(8))) short short8;
typedef __attribute__((ext_vector_type(4))) float floatx4;

#define NUMS 2048
#define DIM 128
#define ROWS_TOT 16384
#define HALF_ROWS 8192
#define KTOP 129
#define SCALE 0.08838834764831845f

__device__ __forceinline__ u16 f2bf(float f) {
  u32 u = __builtin_bit_cast(u32, f);
  u += 0x7FFFu + ((u >> 16) & 1u);
  return (u16)(u >> 16);
}
__device__ __forceinline__ float bf2f(u32 b) {
  return __builtin_bit_cast(float, b << 16);
}
// pack two f32 -> bf16 pair (round-half-up) with one v_perm_b32
__device__ __forceinline__ u32 pack_bf2(float lo, float hi) {
  const u32 a = __builtin_bit_cast(u32, lo) + 0x8000u;
  const u32 b = __builtin_bit_cast(u32, hi) + 0x8000u;
  return __builtin_amdgcn_perm(b, a, 0x07060302u);  // [b.hi16 : a.hi16]
}
// sigmoid via odd Taylor (exact to <2e-4 on [-1,1]; |x|<=0.3 in practice)
__device__ __forceinline__ float sigmoid_poly(float x) {
  const float t = fminf(fmaxf(x, -1.f), 1.f);
  const float t2 = t * t;
  return fmaf(t, fmaf(t2, fmaf(t2, 1.f / 480.f, -1.f / 48.f), 0.25f), 0.5f);
}

// weight fp32 [2048][128] -> wb bf16 [2048][128] + wt bf16 [128][2048]
__global__ void cvt_w_k(const float* __restrict__ w, u16* __restrict__ wb,
                        u16* __restrict__ wt) {
  __shared__ u16 tile[32][33];
  const int tx = threadIdx.x, ty = threadIdx.y;
  const int x = blockIdx.x * 32 + tx;
  const int y0 = blockIdx.y * 32;
#pragma unroll
  for (int j = 0; j < 32; j += 8) {
    const u16 v = f2bf(w[(size_t)(y0 + ty + j) * DIM + x]);
    wb[(size_t)(y0 + ty + j) * DIM + x] = v;
    tile[ty + j][tx] = v;
  }
  __syncthreads();
  const int x2 = y0 + tx;
  const int y2 = blockIdx.x * 32 + ty;
#pragma unroll
  for (int j = 0; j < 32; j += 8)
    wt[(size_t)(y2 + j) * NUMS + x2] = tile[tx][ty + j];
}

__global__ __launch_bounds__(512, 4)
void fused_k(const float* __restrict__ dataF, const u16* __restrict__ wb,
             const u16* __restrict__ wt, float* __restrict__ out) {
  __shared__ u16 S[16 * NUMS];  // 64 KiB; 8-elem chunks XOR-swizzled by row
  const int tid = threadIdx.x;
  const int r0 = blockIdx.x * 16;
  const int lane = tid & 63, wave = tid >> 6;  // 8 waves
  const int m = lane & 15, q = lane >> 4;

  // ---- dfrag: data row r0+m slices, fp32 -> bf16; accumulate ||d||^2 ----
  short8 dfrag[4];
  float nd2 = 0.f;
  {
    const float* ap = dataF + (size_t)(r0 + m) * DIM + q * 8;
#pragma unroll
    for (int ks = 0; ks < 4; ks++) {
      const float4 x = *(const float4*)(ap + ks * 32);
      const float4 y = *(const float4*)(ap + ks * 32 + 4);
      nd2 += x.x * x.x + x.y * x.y + x.z * x.z + x.w * x.w;
      nd2 += y.x * y.x + y.y * y.y + y.z * y.z + y.w * y.w;
      uint4 uv;
      uv.x = pack_bf2(x.x, x.y);
      uv.y = pack_bf2(x.z, x.w);
      uv.z = pack_bf2(y.x, y.y);
      uv.w = pack_bf2(y.z, y.w);
      dfrag[ks] = __builtin_bit_cast(short8, uv);
    }
    nd2 += __shfl_xor(nd2, 16);  // reduce over q -> per-m ||d_row||^2
    nd2 += __shfl_xor(nd2, 32);
  }

  // ---- GEMM1 (transposed): lane = data-row m, att-cols n0 + q*4 + {0..3} ----
  // ds_write addr: chunk = wave*32 + nt*2 + (q>>1); phys = chunk^m decomposes
  // (disjoint bit fields) to wave*32 + 2*(nt^m217) + b0, b0=(q>>1)^(m&1).
  const int m217 = (m >> 1) & 7;
  u16* sbase = S + m * NUMS + wave * 256 + ((((q >> 1) ^ (m & 1)) << 3) | ((q & 1) << 2));
#pragma unroll 4
  for (int nt = 0; nt < 16; nt++) {
    const int n0 = wave * 256 + nt * 16;
    const u16* wp = wb + (size_t)(n0 + m) * DIM + q * 8;
    floatx4 acc = {0.f, 0.f, 0.f, 0.f};
#pragma unroll
    for (int ks = 0; ks < 4; ks++) {
      const short8 wf = *(const short8*)(wp + ks * 32);
      acc = __builtin_amdgcn_mfma_f32_16x16x32_bf16(wf, dfrag[ks], acc, 0, 0, 0);
    }
    uint2 p;
    p.x = pack_bf2(sigmoid_poly(acc[0] * SCALE), sigmoid_poly(acc[1] * SCALE));
    p.y = pack_bf2(sigmoid_poly(acc[2] * SCALE), sigmoid_poly(acc[3] * SCALE));
    *(uint2*)(sbase + ((nt ^ m217) << 4)) = p;
  }
  __syncthreads();

  // ---- first half: read_query = [data_fp32 | attention @ W] ----
  if (r0 < HALF_ROWS) {
    {  // copy fp32 data -> read_query[:, :128]
      const int row = tid >> 5;
      const int c4 = (tid & 31) << 2;
      *(float4*)(out + 16384 + (size_t)(r0 + row) * 256 + c4) =
          *(const float4*)(dataF + (size_t)(r0 + row) * DIM + c4);
    }
    // GEMM2: A = wt rows, B = S rows. Swizzle (ks*4+q)^m decomposed: ks=g*4+e,
    // chunk bits [1:0]=q,[3:2]=e,[7:4]=g -> phys elems =
    // 8*(q^(m&3)) + 32*(e^(m>>2)) + 128*g  (4 base ptrs + imm offsets).
    const int n0 = wave * 16;
    const u16* ap = wt + (size_t)(n0 + m) * NUMS + q * 8;
    const u16* bb[4];
#pragma unroll
    for (int e = 0; e < 4; e++)
      bb[e] = S + m * NUMS + ((q ^ (m & 3)) << 3) + ((e ^ (m >> 2)) << 5);
    floatx4 acc = {0.f, 0.f, 0.f, 0.f};
#pragma unroll 4
    for (int g = 0; g < 16; g++) {
#pragma unroll
      for (int e = 0; e < 4; e++) {
        const short8 a = *(const short8*)(ap + (g * 4 + e) * 32);
        const short8 b = *(const short8*)(bb[e] + g * 128);
        acc = __builtin_amdgcn_mfma_f32_16x16x32_bf16(a, b, acc, 0, 0, 0);
      }
    }
    float4 st;
    st.x = acc[0]; st.y = acc[1]; st.z = acc[2]; st.w = acc[3];
    *(float4*)(out + 16384 + (size_t)(r0 + m) * 256 + 128 + n0 + q * 4) = st;
  }

  // ---- top-129 mean per row (2 rows/wave, in-wave) ----
#pragma unroll
  for (int rv = 0; rv < 2; rv++) {
    const int rr = wave * 2 + rv;
    u32 xh[16];
#pragma unroll
    for (int j = 0; j < 4; j++) {
      const uint4 t = *(const uint4*)(S + rr * NUMS + (j * 64 + lane) * 8);
      xh[j * 4 + 0] = t.x; xh[j * 4 + 1] = t.y;
      xh[j * 4 + 2] = t.z; xh[j * 4 + 3] = t.w;
    }
#pragma unroll
    for (int i = 0; i < 16; i++) xh[i] |= 0x80008000u;  // borrow isolation

    // predicted 129th code: 0x3F00 + 0.8834*||d|| + 0.5 (order statistics)
    const float ndr = __shfl(nd2, rr);
    int BASEi = 0x3F00 + (int)(0.88340f * sqrtf(ndr) + 0.5f) - 2;
    if (BASEi < 0x3F01) BASEi = 0x3F01;
    const u32 BASE = (u32)BASEi;
    const u32 base2 = BASE * 0x10001u;

    // 6 consecutive thresholds BASE..BASE+5, packed block... wave reduce
    u32 c6[6];
#pragma unroll
    for (int j = 0; j < 6; j++) {
      const u32 t2 = base2 + (u32)j * 0x10001u;
      u32 c = 0;
#pragma unroll
      for (int i = 0; i < 16; i++) c += __popc((xh[i] - t2) & 0x80008000u);
      c6[j] = c;
    }
    u32 p3[3];
    p3[0] = c6[0] | (c6[1] << 16);
    p3[1] = c6[2] | (c6[3] << 16);
    p3[2] = c6[4] | (c6[5] << 16);
#pragma unroll
    for (int off = 1; off < 64; off <<= 1) {
#pragma unroll
      for (int j = 0; j < 3; j++) p3[j] += (u32)__shfl_xor((int)p3[j], off);
    }
    u32 cw[6];
#pragma unroll
    for (int j = 0; j < 3; j++) {
      cw[2 * j] = p3[j] & 0xFFFFu;
      cw[2 * j + 1] = p3[j] >> 16;
    }

    if (cw[0] >= KTOP && cw[5] < KTOP) {  // hot: lo in [BASE, BASE+4]
      u32 jj = 0;
#pragma unroll
      for (int j = 1; j < 6; j++) jj += (cw[j] >= KTOP) ? 1u : 0u;
      const u32 lo = BASE + jj;
      u32 cgt = cw[5];
#pragma unroll
      for (int j = 5; j >= 1; j--) if (cw[j] < KTOP) cgt = cw[j];
      // integer sum of (code - lo - 1) over codes > lo (all in [0.5,1) band)
      const u32 tg = (lo + 1u) * 0x10001u;
      u32 s1 = 0;
#pragma unroll
      for (int i = 0; i < 16; i++) {
        const u32 y = xh[i] - tg;
        const u32 sp = (y >> 15) & 0x10001u;
        s1 += y & ((sp << 15) - sp);
      }
      s1 = (s1 & 0xFFFFu) + (s1 >> 16);
#pragma unroll
      for (int off = 1; off < 64; off <<= 1) s1 += (u32)__shfl_xor((int)s1, off);
      if (lane == 0) {
        const float sum_gt = 0.5f * (float)cgt +
            ((float)s1 + (float)cgt * (float)(lo + 1u - 0x3F00u)) * (1.f / 512.f);
        const float vstar = 0.5f + (float)(lo - 0x3F00u) * (1.f / 512.f);
        const float mean =
            (sum_gt + (float)(KTOP - (int)cgt) * vstar) * (1.f / (float)KTOP);
        out[r0 + rr] = 1.f - mean;
      }
    } else {  // exact per-wave secant/bisect fallback (cold)
      auto cnt_ge = [&](u32 t) -> u32 {
        const u32 t2 = t * 0x10001u;
        u32 c = 0;
#pragma unroll
        for (int i = 0; i < 16; i++) c += __popc((xh[i] - t2) & 0x80008000u);
#pragma unroll
        for (int off = 1; off < 64; off <<= 1) c += (u32)__shfl_xor((int)c, off);
        return c;
      };
      u32 L = 0u, cL = 2048u, H = 0x3F81u, cH = 0u;
      u32 t = 0x3F0Au;
      for (int it = 0; it < 24 && H - L > 1u; ++it) {
        const u32 c = cnt_ge(t);
        if (c >= KTOP) { L = t; cL = c; } else { H = t; cH = c; }
        if (H - L <= 1u) break;
        u32 tn;
        if (it < 3) tn = L + ((cL - KTOP) * (H - L)) / (cL - cH);
        else tn = (L + H) >> 1;
        if (tn <= L) tn = L + 1u;
        if (tn >= H) tn = H - 1u;
        t = tn;
      }
      const u32 lo = L, cgt = cH;
      const float vstar = bf2f(lo);
      float s = 0.f;
#pragma unroll
      for (int i = 0; i < 16; i++) {
        const u32 cl = xh[i] & 0x7FFFu;
        const u32 ch = (xh[i] >> 16) & 0x7FFFu;
        if (cl > lo) s += bf2f(cl);
        if (ch > lo) s += bf2f(ch);
      }
#pragma unroll
      for (int off = 1; off < 64; off <<= 1) s += __shfl_xor(s, off);
      if (lane == 0) {
        const float mean =
            (s + (float)(KTOP - (int)cgt) * vstar) * (1.f / (float)KTOP);
        out[r0 + rr] = 1.f - mean;
      }
    }
  }
}

extern "C" void kernel_launch(void* const* d_in, const int* in_sizes, int n_in,
                              void* d_out, int out_size, void* d_ws, size_t ws_size,
                              hipStream_t stream) {
  const float* data = (const float*)d_in[0];    // [32,512,128] fp32
  const float* weight = (const float*)d_in[1];  // [2048,128] fp32
  float* out = (float*)d_out;  // 16384 mem_score + 16*512*256 read_query (fp32)

  u16* wt = (u16*)d_ws;       // [128][2048] bf16, 512 KiB
  u16* wb = wt + NUMS * DIM;  // [2048][128] bf16, 512 KiB

  cvt_w_k<<<dim3(DIM / 32, NUMS / 32), dim3(32, 8), 0, stream>>>(weight, wb, wt);
  fused_k<<<dim3(ROWS_TOT / 16), dim3(512), 0, stream>>>(data, wb, wt, out);
}